// Round 2
// baseline (513.004 us; speedup 1.0000x reference)
//
#include <hip/hip_runtime.h>
#include <stdint.h>

#define DEV static __device__ __forceinline__

typedef __bf16 bf16x8 __attribute__((ext_vector_type(8)));
typedef float f32x4 __attribute__((ext_vector_type(4)));

typedef const __attribute__((address_space(1))) void* as1cp;
typedef __attribute__((address_space(3))) void* as3p;

DEV uint32_t f2bf1(float f) {
  uint32_t u = __builtin_bit_cast(uint32_t, f);
  u += 0x7fffu + ((u >> 16) & 1u);   // RNE
  return u >> 16;
}
DEV uint32_t f2bf2(float lo, float hi) { return f2bf1(lo) | (f2bf1(hi) << 16); }

DEV void gll16(const void* g, void* l) {
  __builtin_amdgcn_global_load_lds((as1cp)g, (as3p)l, 16, 0, 0);
}

// ---------------------------------------------------------------------------
// Projection: out = X @ W^T + b  (M=16384, N=256, K=1024), bf16 MFMA.
// z=0 -> q (scaled by log2(e)/16), z=1 -> k, z=2 -> v stored TRANSPOSED [b][d][s].
// BM=128, BN=256, BK=64, 512 threads (8 waves, 2x4), wave tile 64x64.
// ---------------------------------------------------------------------------
__global__ __launch_bounds__(512) void proj_kernel(
    const float* __restrict__ xq, const float* __restrict__ xk, const float* __restrict__ xv,
    const float* __restrict__ wq, const float* __restrict__ wk, const float* __restrict__ wv,
    const float* __restrict__ bq, const float* __restrict__ bk, const float* __restrict__ bv,
    uint16_t* __restrict__ qo, uint16_t* __restrict__ ko, uint16_t* __restrict__ vo)
{
  const int z = blockIdx.z;
  const float* X  = (z == 0) ? xq : (z == 1) ? xk : xv;
  const float* W  = (z == 0) ? wq : (z == 1) ? wk : wv;
  const float* Bi = (z == 0) ? bq : (z == 1) ? bk : bv;

  const int tid = threadIdx.x;
  const int lane = tid & 63;
  const int w = tid >> 6;
  const int wm = w >> 2, wn = w & 3;
  const int l15 = lane & 15, g = lane >> 4;
  const int m0 = blockIdx.x * 128;

  __shared__ uint16_t sA[128 * 64];   // 16 KB, rows of 128B, XOR-swizzled
  __shared__ uint16_t sB[256 * 64];   // 32 KB

  const int am = tid >> 2, ak = (tid & 3) * 16;   // A staging: row, col
  const int bn = tid >> 1, bkc = (tid & 1) * 32;  // B staging: row, col

  const float* Ap = X + (size_t)(m0 + am) * 1024 + ak;
  const float* Wp = W + (size_t)bn * 1024 + bkc;

  f32x4 acc[4][4];
  #pragma unroll
  for (int i = 0; i < 4; ++i)
    #pragma unroll
    for (int j = 0; j < 4; ++j) { f32x4 zz = {0.f, 0.f, 0.f, 0.f}; acc[i][j] = zz; }

  float ar[16], br[32];
  #pragma unroll
  for (int i = 0; i < 4; ++i) { float4 t = ((const float4*)Ap)[i];
    ar[4*i+0]=t.x; ar[4*i+1]=t.y; ar[4*i+2]=t.z; ar[4*i+3]=t.w; }
  #pragma unroll
  for (int i = 0; i < 8; ++i) { float4 t = ((const float4*)Wp)[i];
    br[4*i+0]=t.x; br[4*i+1]=t.y; br[4*i+2]=t.z; br[4*i+3]=t.w; }

  for (int kt = 0; kt < 16; ++kt) {
    if (kt) __syncthreads();            // previous tile fully consumed
    // stage A: 16 bf16 per thread, 2 x b128, swizzled
    {
      uint32_t ph = (uint32_t)(am * 128 + ak * 2) ^ ((uint32_t)(am & 7) << 4);
      uint4 p0, p1;
      p0.x = f2bf2(ar[0],  ar[1]);  p0.y = f2bf2(ar[2],  ar[3]);
      p0.z = f2bf2(ar[4],  ar[5]);  p0.w = f2bf2(ar[6],  ar[7]);
      p1.x = f2bf2(ar[8],  ar[9]);  p1.y = f2bf2(ar[10], ar[11]);
      p1.z = f2bf2(ar[12], ar[13]); p1.w = f2bf2(ar[14], ar[15]);
      *(uint4*)((char*)sA + ph)        = p0;
      *(uint4*)((char*)sA + (ph ^ 16)) = p1;
      uint32_t pb = (uint32_t)(bn * 128 + bkc * 2) ^ ((uint32_t)(bn & 7) << 4);
      #pragma unroll
      for (int c = 0; c < 4; ++c) {
        uint4 pq;
        pq.x = f2bf2(br[8*c+0], br[8*c+1]); pq.y = f2bf2(br[8*c+2], br[8*c+3]);
        pq.z = f2bf2(br[8*c+4], br[8*c+5]); pq.w = f2bf2(br[8*c+6], br[8*c+7]);
        *(uint4*)((char*)sB + (pb ^ (16 * c))) = pq;
      }
    }
    __syncthreads();                    // tile visible to all waves
    if (kt < 15) {                      // prefetch next tile under the MFMAs
      const float* Ap2 = Ap + (kt + 1) * 64;
      const float* Wp2 = Wp + (kt + 1) * 64;
      #pragma unroll
      for (int i = 0; i < 4; ++i) { float4 t = ((const float4*)Ap2)[i];
        ar[4*i+0]=t.x; ar[4*i+1]=t.y; ar[4*i+2]=t.z; ar[4*i+3]=t.w; }
      #pragma unroll
      for (int i = 0; i < 8; ++i) { float4 t = ((const float4*)Wp2)[i];
        br[4*i+0]=t.x; br[4*i+1]=t.y; br[4*i+2]=t.z; br[4*i+3]=t.w; }
    }
    #pragma unroll
    for (int ks = 0; ks < 2; ++ks) {
      bf16x8 fa[4], fb[4];
      #pragma unroll
      for (int f = 0; f < 4; ++f) {
        uint32_t row = wm * 64 + 16 * f + l15;
        fa[f] = *(const bf16x8*)((char*)sA + row * 128 +
                 (((uint32_t)(ks * 64 + g * 16)) ^ ((row & 7) << 4)));
      }
      #pragma unroll
      for (int f = 0; f < 4; ++f) {
        uint32_t row = wn * 64 + 16 * f + l15;
        fb[f] = *(const bf16x8*)((char*)sB + row * 128 +
                 (((uint32_t)(ks * 64 + g * 16)) ^ ((row & 7) << 4)));
      }
      #pragma unroll
      for (int fm = 0; fm < 4; ++fm)
        #pragma unroll
        for (int fn = 0; fn < 4; ++fn)
          acc[fm][fn] = __builtin_amdgcn_mfma_f32_16x16x32_bf16(fa[fm], fb[fn], acc[fm][fn], 0, 0, 0);
    }
  }

  // epilogue: C row = wm*64+16*fm+4*g+r, col = wn*64+16*fn+l15
  #pragma unroll
  for (int fn = 0; fn < 4; ++fn) {
    const int n = wn * 64 + 16 * fn + l15;
    const float bias = Bi[n];
    #pragma unroll
    for (int fm = 0; fm < 4; ++fm) {
      const int mg = m0 + wm * 64 + 16 * fm + 4 * g;
      if (z == 0) {
        #pragma unroll
        for (int r = 0; r < 4; ++r)
          qo[(size_t)(mg + r) * 256 + n] =
              (uint16_t)f2bf1((acc[fm][fn][r] + bias) * 0.09016844f); // log2(e)/16
      } else if (z == 1) {
        #pragma unroll
        for (int r = 0; r < 4; ++r)
          ko[(size_t)(mg + r) * 256 + n] = (uint16_t)f2bf1(acc[fm][fn][r] + bias);
      } else {
        // vT[b][d][s]: lane's 4 consecutive rows pack into one 8B store
        uint2 pv;
        pv.x = f2bf2(acc[fm][fn][0] + bias, acc[fm][fn][1] + bias);
        pv.y = f2bf2(acc[fm][fn][2] + bias, acc[fm][fn][3] + bias);
        *(uint2*)(vo + (((size_t)(mg >> 12)) << 20) + (((size_t)n) << 12) + (mg & 4095)) = pv;
      }
    }
  }
}

// ---------------------------------------------------------------------------
// Flash attention: QBLK=64 (4 waves x 16 q-rows), KVBLK=64, online softmax.
// K staged [kv][256] swizzled; V staged from vT as [d][64] swizzled.
// Double-buffered via global_load_lds with pre-swizzled global source.
// ---------------------------------------------------------------------------
__global__ __launch_bounds__(256) void attn_kernel(
    const uint16_t* __restrict__ qg, const uint16_t* __restrict__ kg,
    const uint16_t* __restrict__ vg, float* __restrict__ out)
{
  extern __shared__ char smem[];
  char* sKb = smem;             // 2 x 32768
  char* sVb = smem + 65536;     // 2 x 32768
  char* sPb = smem + 131072;    // 4 waves x 2048

  // XCD-aware swizzle: one batch per XCD pair -> per-XCD K/V set = 4MB = L2
  const int bid = blockIdx.x;
  const int xcd = bid & 7, slot = bid >> 3;
  const int batch = xcd >> 1;
  const int q0 = ((((xcd & 1) << 5) + slot)) * 64;

  const int tid = threadIdx.x;
  const int lane = tid & 63;
  const int w = tid >> 6;
  const int l15 = lane & 15, g = lane >> 4;
  const int wbase = tid & ~63;

  const size_t rowb = (size_t)batch * 4096;

  bf16x8 qf[8];
  {
    const uint16_t* qp = qg + (rowb + q0 + w * 16 + l15) * 256;
    #pragma unroll
    for (int ks = 0; ks < 8; ++ks) qf[ks] = *(const bf16x8*)(qp + ks * 32 + g * 8);
  }

  f32x4 o[16];
  #pragma unroll
  for (int i = 0; i < 16; ++i) { f32x4 zz = {0.f, 0.f, 0.f, 0.f}; o[i] = zz; }
  float mrow[4], lrow[4];
  #pragma unroll
  for (int r = 0; r < 4; ++r) { mrow[r] = -1e30f; lrow[r] = 0.f; }

  const char* kgb = (const char*)(kg + rowb * 256);                 // [s][256] bf16
  const char* vgb = (const char*)(vg + (size_t)batch * 256 * 4096); // [d][4096] bf16

  auto STAGE = [&](int buf, int t) {
    const int kv0 = t * 64;
    #pragma unroll
    for (int i = 0; i < 8; ++i) {        // K tile: 64 rows x 512B
      const int widx = i * 256 + wbase;
      uint32_t L = (uint32_t)(widx + lane) * 16;
      uint32_t U = L ^ (((L >> 9) & 7u) << 4);   // inverse-swizzled source
      const char* src = kgb + (size_t)(kv0 + (U >> 9)) * 512 + (U & 511);
      gll16(src, sKb + buf * 32768 + widx * 16);
    }
    #pragma unroll
    for (int i = 0; i < 8; ++i) {        // V tile: 256 rows x 128B (from vT)
      const int widx = i * 256 + wbase;
      uint32_t L = (uint32_t)(widx + lane) * 16;
      uint32_t U = L ^ (((L >> 7) & 7u) << 4);
      const char* src = vgb + (size_t)(U >> 7) * 8192 + (size_t)kv0 * 2 + (U & 127);
      gll16(src, sVb + buf * 32768 + widx * 16);
    }
  };

  STAGE(0, 0);
  char* Pw = sPb + w * 2048;

  for (int t = 0; t < 64; ++t) {
    __syncthreads();                     // drains STAGE(t) (vmcnt 0) + barrier
    if (t + 1 < 64) STAGE((t + 1) & 1, t + 1);   // next tile flies under compute

    const char* Kb = sKb + (t & 1) * 32768;
    const char* Vb = sVb + (t & 1) * 32768;

    // S = Q K^T : rows q=4g+r, cols kv=16f+l15
    f32x4 s4[4];
    #pragma unroll
    for (int f = 0; f < 4; ++f) { f32x4 zz = {0.f, 0.f, 0.f, 0.f}; s4[f] = zz; }
    #pragma unroll
    for (int ks = 0; ks < 8; ++ks) {
      bf16x8 kf[4];
      #pragma unroll
      for (int f = 0; f < 4; ++f) {
        uint32_t row = 16 * f + l15;
        kf[f] = *(const bf16x8*)(Kb + row * 512 +
                 (((uint32_t)(ks * 64 + g * 16)) ^ ((row & 7) << 4)));
      }
      #pragma unroll
      for (int f = 0; f < 4; ++f)
        s4[f] = __builtin_amdgcn_mfma_f32_16x16x32_bf16(qf[ks], kf[f], s4[f], 0, 0, 0);
    }

    // online softmax (exp2 domain; scale folded into q)
    float sc[4], ps[4][4];
    #pragma unroll
    for (int r = 0; r < 4; ++r) {
      float mx = fmaxf(fmaxf(s4[0][r], s4[1][r]), fmaxf(s4[2][r], s4[3][r]));
      mx = fmaxf(mx, __shfl_xor(mx, 1, 64));
      mx = fmaxf(mx, __shfl_xor(mx, 2, 64));
      mx = fmaxf(mx, __shfl_xor(mx, 4, 64));
      mx = fmaxf(mx, __shfl_xor(mx, 8, 64));
      float mn = fmaxf(mrow[r], mx);
      sc[r] = exp2f(mrow[r] - mn);
      mrow[r] = mn;
      float sum = 0.f;
      #pragma unroll
      for (int f = 0; f < 4; ++f) { ps[f][r] = exp2f(s4[f][r] - mn); sum += ps[f][r]; }
      sum += __shfl_xor(sum, 1, 64);
      sum += __shfl_xor(sum, 2, 64);
      sum += __shfl_xor(sum, 4, 64);
      sum += __shfl_xor(sum, 8, 64);
      lrow[r] = lrow[r] * sc[r] + sum;
    }
    #pragma unroll
    for (int i = 0; i < 16; ++i)
      #pragma unroll
      for (int r = 0; r < 4; ++r) o[i][r] *= sc[r];

    // P -> LDS (per-wave region, swizzled)
    #pragma unroll
    for (int f = 0; f < 4; ++f)
      #pragma unroll
      for (int r = 0; r < 4; ++r) {
        uint32_t row = 4 * g + r;
        *(uint16_t*)(Pw + row * 128 +
            (((uint32_t)((16 * f + l15) * 2)) ^ ((row & 7) << 4))) = (uint16_t)f2bf1(ps[f][r]);
      }

    // O += P V
    #pragma unroll
    for (int ks2 = 0; ks2 < 2; ++ks2) {
      bf16x8 pa = *(const bf16x8*)(Pw + l15 * 128 +
                   (((uint32_t)(ks2 * 64 + g * 16)) ^ ((l15 & 7) << 4)));
      #pragma unroll
      for (int fd = 0; fd < 16; ++fd) {
        uint32_t row = 16 * fd + l15;
        bf16x8 vb = *(const bf16x8*)(Vb + row * 128 +
                     (((uint32_t)(ks2 * 64 + g * 16)) ^ ((row & 7) << 4)));
        o[fd] = __builtin_amdgcn_mfma_f32_16x16x32_bf16(pa, vb, o[fd], 0, 0, 0);
      }
    }
  }

  float* op = out + (rowb + q0 + w * 16) * 256;
  #pragma unroll
  for (int r = 0; r < 4; ++r) {
    float inv = 1.f / lrow[r];
    #pragma unroll
    for (int fd = 0; fd < 16; ++fd)
      op[(4 * g + r) * 256 + 16 * fd + l15] = o[fd][r] * inv;
  }
}

// ---------------------------------------------------------------------------
extern "C" void kernel_launch(void* const* d_in, const int* in_sizes, int n_in,
                              void* d_out, int out_size, void* d_ws, size_t ws_size,
                              hipStream_t stream) {
  const float* xq = (const float*)d_in[0];
  const float* xk = (const float*)d_in[1];
  const float* xv = (const float*)d_in[2];
  // d_in[3] = mask (unused by reference forward)
  const float* wq = (const float*)d_in[4];
  const float* bq = (const float*)d_in[5];
  const float* wk = (const float*)d_in[6];
  const float* bk = (const float*)d_in[7];
  const float* wv = (const float*)d_in[8];
  const float* bv = (const float*)d_in[9];

  uint16_t* qws = (uint16_t*)d_ws;                       // [4][4096][256] bf16
  uint16_t* kws = qws + (size_t)4 * 4096 * 256;          // [4][4096][256] bf16
  uint16_t* vws = kws + (size_t)4 * 4096 * 256;          // [4][256][4096] bf16 (V^T)

  proj_kernel<<<dim3(128, 1, 3), 512, 0, stream>>>(
      xq, xk, xv, wq, wk, wv, bq, bk, bv, qws, kws, vws);

  (void)hipFuncSetAttribute((const void*)attn_kernel,
                            hipFuncAttributeMaxDynamicSharedMemorySize, 139264);
  attn_kernel<<<dim3(256), 256, 139264, stream>>>(qws, kws, vws, (float*)d_out);
}

// Round 4
// 446.642 us; speedup vs baseline: 1.1486x; 1.1486x over previous
//
#include <hip/hip_runtime.h>
#include <stdint.h>

#define DEV static __device__ __forceinline__

typedef __bf16 bf16x8 __attribute__((ext_vector_type(8)));
typedef float f32x4 __attribute__((ext_vector_type(4)));

typedef const __attribute__((address_space(1))) void* as1cp;
typedef __attribute__((address_space(3))) void* as3p;

DEV uint32_t f2bf1(float f) {
  uint32_t u = __builtin_bit_cast(uint32_t, f);
  u += 0x7fffu + ((u >> 16) & 1u);   // RNE
  return u >> 16;
}
DEV uint32_t f2bf2(float lo, float hi) { return f2bf1(lo) | (f2bf1(hi) << 16); }
DEV float bf2f(uint32_t h) { return __builtin_bit_cast(float, h << 16); }

DEV void gll16(const void* g, void* l) {
  __builtin_amdgcn_global_load_lds((as1cp)g, (as3p)l, 16, 0, 0);
}

// ---------------------------------------------------------------------------
// Projection: out = X @ W^T + b  (M=16384, N=256, K=1024), bf16 MFMA.
// v3: BM=128, BN=128 (N split in 2), grid 128x2x3 = 768 blocks = 3 blocks/CU.
// 256 threads (4 waves, 2x2), wave tile 64x64. A prefetched in regs; W loaded
// at stage time (L2-hot, covered by co-resident blocks).
// z=0 -> q (scaled log2(e)/16), z=1 -> k, z=2 -> v TRANSPOSED [b][d][s].
// ---------------------------------------------------------------------------
__global__ __launch_bounds__(256, 3) void proj_kernel(
    const float* __restrict__ xq, const float* __restrict__ xk, const float* __restrict__ xv,
    const float* __restrict__ wq, const float* __restrict__ wk, const float* __restrict__ wv,
    const float* __restrict__ bq, const float* __restrict__ bk, const float* __restrict__ bv,
    uint16_t* __restrict__ qo, uint16_t* __restrict__ ko, uint16_t* __restrict__ vo)
{
  const int z = blockIdx.z;
  const float* X  = (z == 0) ? xq : (z == 1) ? xk : xv;
  const float* W  = (z == 0) ? wq : (z == 1) ? wk : wv;
  const float* Bi = (z == 0) ? bq : (z == 1) ? bk : bv;

  const int tid = threadIdx.x;
  const int lane = tid & 63;
  const int w = tid >> 6;
  const int wm = w >> 1, wn = w & 1;
  const int l15 = lane & 15, g = lane >> 4;
  const int m0 = blockIdx.x * 128;
  const int n0 = blockIdx.y * 128;

  __shared__ uint16_t sA[128 * 64];   // 16 KB, rows 128B, XOR-swizzled
  __shared__ uint16_t sB[128 * 64];   // 16 KB

  const int am = tid >> 1, ak = (tid & 1) * 32;   // shared A/W staging split
  const float* Ap = X + (size_t)(m0 + am) * 1024 + ak;
  const float* Wp = W + (size_t)(n0 + am) * 1024 + ak;

  f32x4 acc[4][4];
  #pragma unroll
  for (int i = 0; i < 4; ++i)
    #pragma unroll
    for (int j = 0; j < 4; ++j) { f32x4 zz = {0.f, 0.f, 0.f, 0.f}; acc[i][j] = zz; }

  float ar[32];
  #pragma unroll
  for (int i = 0; i < 8; ++i) { float4 t = ((const float4*)Ap)[i];
    ar[4*i+0]=t.x; ar[4*i+1]=t.y; ar[4*i+2]=t.z; ar[4*i+3]=t.w; }

  const uint32_t ph = (uint32_t)(am * 128 + ak * 2) ^ ((uint32_t)(am & 7) << 4);

  for (int kt = 0; kt < 16; ++kt) {
    if (kt) __syncthreads();            // previous tile fully consumed
    // stage A from prefetched regs
    #pragma unroll
    for (int c = 0; c < 4; ++c) {
      uint4 p;
      p.x = f2bf2(ar[8*c+0], ar[8*c+1]); p.y = f2bf2(ar[8*c+2], ar[8*c+3]);
      p.z = f2bf2(ar[8*c+4], ar[8*c+5]); p.w = f2bf2(ar[8*c+6], ar[8*c+7]);
      *(uint4*)((char*)sA + (ph ^ (16u * c))) = p;
    }
    // load + stage W (L2-hot after first block touches it)
    {
      float wr[32];
      const float* Wk = Wp + kt * 64;
      #pragma unroll
      for (int i = 0; i < 8; ++i) { float4 t = ((const float4*)Wk)[i];
        wr[4*i+0]=t.x; wr[4*i+1]=t.y; wr[4*i+2]=t.z; wr[4*i+3]=t.w; }
      #pragma unroll
      for (int c = 0; c < 4; ++c) {
        uint4 p;
        p.x = f2bf2(wr[8*c+0], wr[8*c+1]); p.y = f2bf2(wr[8*c+2], wr[8*c+3]);
        p.z = f2bf2(wr[8*c+4], wr[8*c+5]); p.w = f2bf2(wr[8*c+6], wr[8*c+7]);
        *(uint4*)((char*)sB + (ph ^ (16u * c))) = p;
      }
    }
    __syncthreads();                    // tile visible
    if (kt < 15) {                      // prefetch next A under MFMAs
      const float* Ap2 = Ap + (kt + 1) * 64;
      #pragma unroll
      for (int i = 0; i < 8; ++i) { float4 t = ((const float4*)Ap2)[i];
        ar[4*i+0]=t.x; ar[4*i+1]=t.y; ar[4*i+2]=t.z; ar[4*i+3]=t.w; }
    }
    #pragma unroll
    for (int ks = 0; ks < 2; ++ks) {
      bf16x8 fa[4], fb[4];
      #pragma unroll
      for (int f = 0; f < 4; ++f) {
        uint32_t row = wm * 64 + 16 * f + l15;
        fa[f] = *(const bf16x8*)((char*)sA + row * 128 +
                 (((uint32_t)(ks * 64 + g * 16)) ^ ((row & 7) << 4)));
      }
      #pragma unroll
      for (int f = 0; f < 4; ++f) {
        uint32_t row = wn * 64 + 16 * f + l15;
        fb[f] = *(const bf16x8*)((char*)sB + row * 128 +
                 (((uint32_t)(ks * 64 + g * 16)) ^ ((row & 7) << 4)));
      }
      #pragma unroll
      for (int fm = 0; fm < 4; ++fm)
        #pragma unroll
        for (int fn = 0; fn < 4; ++fn)
          acc[fm][fn] = __builtin_amdgcn_mfma_f32_16x16x32_bf16(fa[fm], fb[fn], acc[fm][fn], 0, 0, 0);
    }
  }

  // epilogue: C row = m0+wm*64+16fm+4g+r, col = n0+wn*64+16fn+l15
  #pragma unroll
  for (int fn = 0; fn < 4; ++fn) {
    const int n = n0 + wn * 64 + 16 * fn + l15;
    const float bias = Bi[n];
    #pragma unroll
    for (int fm = 0; fm < 4; ++fm) {
      const int mg = m0 + wm * 64 + 16 * fm + 4 * g;
      if (z == 0) {
        #pragma unroll
        for (int r = 0; r < 4; ++r)
          qo[(size_t)(mg + r) * 256 + n] =
              (uint16_t)f2bf1((acc[fm][fn][r] + bias) * 0.09016844f); // log2(e)/16
      } else if (z == 1) {
        #pragma unroll
        for (int r = 0; r < 4; ++r)
          ko[(size_t)(mg + r) * 256 + n] = (uint16_t)f2bf1(acc[fm][fn][r] + bias);
      } else {
        uint2 pv;
        pv.x = f2bf2(acc[fm][fn][0] + bias, acc[fm][fn][1] + bias);
        pv.y = f2bf2(acc[fm][fn][2] + bias, acc[fm][fn][3] + bias);
        *(uint2*)(vo + (((size_t)(mg >> 12)) << 20) + (((size_t)n) << 12) + (mg & 4095)) = pv;
      }
    }
  }
}

// ---------------------------------------------------------------------------
// Flash attention v3: 512 thr = 4 q-waves x 2 KV-halves; KVBLK=32, LDS-staged
// double-buffered per half via global_load_lds; flash-merge of halves at end.
// LDS 136KB: K[h][buf] 4x16KB | V[h][buf] 4x16KB | P 8x1KB; merge aliases K.
// K rows 512B w/ (row&7)<<4 XOR (2-way=free). V as 16 contiguous 1KB blocks
// [fd][16d][4g] -> PV frag reads exact-tile contiguous (conflict-free).
// P write ^(g<<4) -> 2-way free; read 1 b128/tile (8-way, ~25cyc).
// ---------------------------------------------------------------------------
__global__ __launch_bounds__(512) void attn_kernel(
    const uint16_t* __restrict__ qg, const uint16_t* __restrict__ kg,
    const uint16_t* __restrict__ vg, float* __restrict__ out)
{
  extern __shared__ char smem[];

  const int bid = blockIdx.x;
  const int xcd = bid & 7, slot = bid >> 3;
  const int batch = xcd >> 1;                       // batch pinned to XCD pair
  const int q0 = (((xcd & 1) << 5) + slot) * 64;

  const int tid = threadIdx.x;
  const int lane = tid & 63;
  const int w = tid >> 6;
  const int hv = w >> 2;                  // KV half (0: even tiles, 1: odd)
  const int wq = w & 3;                   // q sub-tile
  const int l15 = lane & 15, g = lane >> 4;
  const size_t rowb = (size_t)batch * 4096;

  bf16x8 qf[8];
  {
    const uint16_t* qp = qg + (rowb + q0 + wq * 16 + l15) * 256;
    #pragma unroll
    for (int ks = 0; ks < 8; ++ks) qf[ks] = *(const bf16x8*)(qp + ks * 32 + g * 8);
  }

  f32x4 o[16];
  #pragma unroll
  for (int i = 0; i < 16; ++i) { f32x4 zz = {0.f, 0.f, 0.f, 0.f}; o[i] = zz; }
  float mrow[4], lrow[4];
  #pragma unroll
  for (int r = 0; r < 4; ++r) { mrow[r] = -1e30f; lrow[r] = 0.f; }

  const char* kgb = (const char*)(kg + rowb * 256);                 // K [s][256]
  const char* vgb = (const char*)(vg + (size_t)batch * 256 * 4096); // V^T [d][4096]

  auto STAGE = [&](int h, int buf, int t) {
    const int kv0 = (2 * t + h) * 32;
    char* kd = smem + (size_t)(h * 2 + buf) * 16384;
    char* vd = smem + 65536 + (size_t)(h * 2 + buf) * 16384;
    #pragma unroll
    for (int r2 = 0; r2 < 2; ++r2) {
      uint32_t L = (uint32_t)(tid + r2 * 512) * 16;
      // K: dest linear; source pre-swizzled (involution on bits 4-6)
      uint32_t U = L ^ (((L >> 9) & 7u) << 4);
      gll16(kgb + (size_t)(kv0 + (U >> 9)) * 512 + (U & 511), kd + L);
      // V: [fd][16 d][4 g] blocks; slot L holds V[d = L>>6][kv0+8*((L>>4)&3)..+8]
      uint32_t d = L >> 6;
      uint32_t kvo = (L >> 4) & 3u;
      gll16(vgb + (size_t)d * 8192 + (size_t)(kv0 + 8 * kvo) * 2, vd + L);
    }
  };

  STAGE(0, 0, 0); STAGE(1, 0, 0);
  char* Pw = smem + 131072 + (size_t)w * 1024;
  int buf = 0;

  for (int t = 0; t < 64; ++t) {
    __syncthreads();                     // drains stage(t) (vmcnt 0) + barrier
    if (t + 1 < 64) { STAGE(0, buf ^ 1, t + 1); STAGE(1, buf ^ 1, t + 1); }

    const char* Kb = smem + (size_t)(hv * 2 + buf) * 16384;
    const char* Vb = smem + 65536 + (size_t)(hv * 2 + buf) * 16384;

    // ---- S = Q K^T : q-row = 4g+r, kv = 16f+l15
    f32x4 s4[2];
    #pragma unroll
    for (int f = 0; f < 2; ++f) { f32x4 zz = {0.f, 0.f, 0.f, 0.f}; s4[f] = zz; }
    #pragma unroll
    for (int ks = 0; ks < 8; ++ks) {
      bf16x8 kf[2];
      #pragma unroll
      for (int f = 0; f < 2; ++f) {
        uint32_t row = 16 * f + l15;
        kf[f] = *(const bf16x8*)(Kb + row * 512 +
                 (((uint32_t)(ks * 64 + g * 16)) ^ ((l15 & 7) << 4)));
      }
      #pragma unroll
      for (int f = 0; f < 2; ++f)
        s4[f] = __builtin_amdgcn_mfma_f32_16x16x32_bf16(qf[ks], kf[f], s4[f], 0, 0, 0);
    }

    // ---- online softmax (exp2 domain) + defer-max (T13, THR=8)
    float mx[4];
    #pragma unroll
    for (int r = 0; r < 4; ++r) {
      float m2 = fmaxf(s4[0][r], s4[1][r]);
      m2 = fmaxf(m2, __shfl_xor(m2, 1, 64));
      m2 = fmaxf(m2, __shfl_xor(m2, 2, 64));
      m2 = fmaxf(m2, __shfl_xor(m2, 4, 64));
      m2 = fmaxf(m2, __shfl_xor(m2, 8, 64));
      mx[r] = m2;
    }
    int stable = (mx[0] <= mrow[0] + 8.f) && (mx[1] <= mrow[1] + 8.f) &&
                 (mx[2] <= mrow[2] + 8.f) && (mx[3] <= mrow[3] + 8.f);
    if (!__all(stable)) {
      float sc[4];
      #pragma unroll
      for (int r = 0; r < 4; ++r) {
        float mn = fmaxf(mrow[r], mx[r]);
        sc[r] = exp2f(mrow[r] - mn);
        mrow[r] = mn;
        lrow[r] *= sc[r];
      }
      #pragma unroll
      for (int j = 0; j < 16; ++j)
        #pragma unroll
        for (int r = 0; r < 4; ++r) o[j][r] *= sc[r];
    }
    float ps[2][4];
    #pragma unroll
    for (int r = 0; r < 4; ++r) {
      float sum = 0.f;
      #pragma unroll
      for (int f = 0; f < 2; ++f) { ps[f][r] = exp2f(s4[f][r] - mrow[r]); sum += ps[f][r]; }
      sum += __shfl_xor(sum, 1, 64);
      sum += __shfl_xor(sum, 2, 64);
      sum += __shfl_xor(sum, 4, 64);
      sum += __shfl_xor(sum, 8, 64);
      lrow[r] += sum;
    }

    // ---- P -> per-wave LDS: row=4g+r (64B rows), offset ^(g<<4): 2-way free
    #pragma unroll
    for (int f = 0; f < 2; ++f)
      #pragma unroll
      for (int r = 0; r < 4; ++r)
        *(uint16_t*)(Pw + (4 * g + r) * 64 +
            (((uint32_t)(32 * f + 2 * l15)) ^ ((uint32_t)g << 4))) = (uint16_t)f2bf1(ps[f][r]);

    // ---- O += P V : A-frag = P row l15, kv-block g^(l15>>2) un-XOR
    bf16x8 pa = *(const bf16x8*)(Pw + l15 * 64 + 16 * (g ^ (l15 >> 2)));
    #pragma unroll
    for (int fd = 0; fd < 16; ++fd) {
      bf16x8 vbf = *(const bf16x8*)(Vb + fd * 1024 + l15 * 64 + g * 16);
      o[fd] = __builtin_amdgcn_mfma_f32_16x16x32_bf16(pa, vbf, o[fd], 0, 0, 0);
    }

    buf ^= 1;
  }

  // ---- merge the two KV halves (flash combine); merge buffers alias K region
  float*    mlb = (float*)smem;             // [2][4][64][4] = 8 KB
  uint32_t* ob  = (uint32_t*)(smem + 8192); // [4][32][64]   = 32 KB
  __syncthreads();                          // all compute done; K/V/P dead
  if (hv == 1) {
    #pragma unroll
    for (int r = 0; r < 4; ++r) {
      mlb[((0 * 4 + wq) * 64 + lane) * 4 + r] = mrow[r];
      mlb[((1 * 4 + wq) * 64 + lane) * 4 + r] = lrow[r];
    }
    #pragma unroll
    for (int fd = 0; fd < 16; ++fd)
      #pragma unroll
      for (int p = 0; p < 2; ++p)
        ob[(wq * 32 + fd * 2 + p) * 64 + lane] = f2bf2(o[fd][2 * p], o[fd][2 * p + 1]);
  }
  __syncthreads();
  if (hv == 0) {
    float a[4], b2[4], inv[4];
    #pragma unroll
    for (int r = 0; r < 4; ++r) {
      float mu = mlb[((0 * 4 + wq) * 64 + lane) * 4 + r];
      float lu = mlb[((1 * 4 + wq) * 64 + lane) * 4 + r];
      float mn = fmaxf(mrow[r], mu);
      a[r]  = exp2f(mrow[r] - mn);
      b2[r] = exp2f(mu - mn);
      inv[r] = 1.f / (lrow[r] * a[r] + lu * b2[r]);
    }
    float* op = out + (rowb + q0 + wq * 16) * 256;
    #pragma unroll
    for (int fd = 0; fd < 16; ++fd) {
      #pragma unroll
      for (int p = 0; p < 2; ++p) {
        uint32_t u = ob[(wq * 32 + fd * 2 + p) * 64 + lane];
        float vlo = bf2f(u & 0xffffu), vhi = bf2f(u >> 16);
        int r0 = 2 * p, r1 = 2 * p + 1;
        op[(4 * g + r0) * 256 + 16 * fd + l15] =
            (o[fd][r0] * a[r0] + vlo * b2[r0]) * inv[r0];
        op[(4 * g + r1) * 256 + 16 * fd + l15] =
            (o[fd][r1] * a[r1] + vhi * b2[r1]) * inv[r1];
      }
    }
  }
}

// ---------------------------------------------------------------------------
extern "C" void kernel_launch(void* const* d_in, const int* in_sizes, int n_in,
                              void* d_out, int out_size, void* d_ws, size_t ws_size,
                              hipStream_t stream) {
  const float* xq = (const float*)d_in[0];
  const float* xk = (const float*)d_in[1];
  const float* xv = (const float*)d_in[2];
  // d_in[3] = mask (unused by reference forward)
  const float* wq = (const float*)d_in[4];
  const float* bq = (const float*)d_in[5];
  const float* wk = (const float*)d_in[6];
  const float* bk = (const float*)d_in[7];
  const float* wv = (const float*)d_in[8];
  const float* bv = (const float*)d_in[9];

  uint16_t* qws = (uint16_t*)d_ws;                       // [4][4096][256] bf16
  uint16_t* kws = qws + (size_t)4 * 4096 * 256;          // [4][4096][256] bf16
  uint16_t* vws = kws + (size_t)4 * 4096 * 256;          // [4][256][4096] bf16 (V^T)

  proj_kernel<<<dim3(128, 2, 3), 256, 0, stream>>>(
      xq, xk, xv, wq, wk, wv, bq, bk, bv, qws, kws, vws);

  (void)hipFuncSetAttribute((const void*)attn_kernel,
                            hipFuncAttributeMaxDynamicSharedMemorySize, 139264);
  attn_kernel<<<dim3(256), 512, 139264, stream>>>(qws, kws, vws, (float*)d_out);
}